// Round 5
// baseline (230.942 us; speedup 1.0000x reference)
//
#include <hip/hip_runtime.h>
#include <math.h>

typedef unsigned short u16;
typedef unsigned int u32;
typedef __attribute__((ext_vector_type(8))) short short8;
typedef __attribute__((ext_vector_type(4))) float f32x4;

#define BB 2
#define TT 2048
#define EE 1024
#define HH 16
#define HDD 64
#define NC 32
#define CS 64

__device__ __forceinline__ float bf2f(u16 u){ union{unsigned i; float f;} v; v.i=((unsigned)u)<<16; return v.f; }
__device__ __forceinline__ u16 f2bf(float f){ union{float f; unsigned i;} v; v.f=f; return (u16)((v.i + 0x7fffu + ((v.i>>16)&1u))>>16); }

__device__ __forceinline__ void gload16(const void* g, void* l){
    __builtin_amdgcn_global_load_lds((const __attribute__((address_space(1))) void*)g,
                                     (__attribute__((address_space(3))) void*)l, 16, 0, 0);
}

// ---------------------------------------------------------------------------
// f32 -> bf16 conversion with GEMM chunk swizzle baked into global layout.
// ---------------------------------------------------------------------------
__global__ __launch_bounds__(256)
void cvt_swz(const float* __restrict__ s0, const float* __restrict__ s1,
             const float* __restrict__ s2, const float* __restrict__ s3,
             const float* __restrict__ s4, const float* __restrict__ s5,
             u16* __restrict__ d0, u16* __restrict__ d1, u16* __restrict__ d2,
             u16* __restrict__ d3, u16* __restrict__ d4, u16* __restrict__ d5)
{
    const float* S; u16* D; int nch;
    switch (blockIdx.z) {
        case 0: S=s0; D=d0; nch=4096*128; break;
        case 1: S=s1; D=d1; nch=1024*128; break;
        case 2: S=s2; D=d2; nch=1024*128; break;
        case 3: S=s3; D=d3; nch=1024*128; break;
        case 4: S=s4; D=d4; nch=1024*128; break;
        default:S=s5; D=d5; nch=1024*128; break;
    }
    int ci = blockIdx.x*256 + threadIdx.x;
    if (ci >= nch) return;
    int r = ci >> 7, c = ci & 127;
    int pc = (c & ~3) | ((c & 3) ^ ((r >> 1) & 3));
    const float4* sp = (const float4*)(S + (size_t)r*EE + c*8);
    float4 f0 = sp[0], f1 = sp[1];
    short8 ov; u16* o = (u16*)&ov;
    o[0]=f2bf(f0.x); o[1]=f2bf(f0.y); o[2]=f2bf(f0.z); o[3]=f2bf(f0.w);
    o[4]=f2bf(f1.x); o[5]=f2bf(f1.y); o[6]=f2bf(f1.z); o[7]=f2bf(f1.w);
    *(short8*)(D + (size_t)r*EE + pc*8) = ov;
}

// ---------------------------------------------------------------------------
__global__ __launch_bounds__(256)
void trig_tab(float* __restrict__ ctab, float* __restrict__ stab)
{
    int idx = blockIdx.x*256 + threadIdx.x;   // 65536
    int t = idx >> 5, f = idx & 31;
    float ang = (float)t * exp2f(-(float)f * (13.287712379549449f/32.f));
    ctab[idx] = cosf(ang);
    stab[idx] = sinf(ang);
}

// ---------------------------------------------------------------------------
// Fused QKVG projections: 256x256 tile, 8 waves, ring-3 LDS, counted vmcnt.
// One barrier per K-step; loads stay in flight across barriers (never vmcnt 0
// in the main loop). Q,K written with retention d-chunk swizzle.
// ---------------------------------------------------------------------------
__global__ __launch_bounds__(512)
void gemm_qkvg(const u16* __restrict__ A,
               const u16* __restrict__ W0, const u16* __restrict__ W1,
               const u16* __restrict__ W2, const u16* __restrict__ W3,
               const float* __restrict__ b0, const float* __restrict__ b1,
               const float* __restrict__ b2, const float* __restrict__ b3,
               u16* __restrict__ C0, u16* __restrict__ C1,
               u16* __restrict__ C2, u16* __restrict__ C3)
{
    __shared__ u16 SA[3][256*32];   // 48 KB
    __shared__ u16 SB[3][256*32];   // 48 KB
    const u16* W; const float* bias; u16* C; int swz;
    switch (blockIdx.z) {
        case 0: W=W0; bias=b0; C=C0; swz=1; break;
        case 1: W=W1; bias=b1; C=C1; swz=1; break;
        case 2: W=W2; bias=b2; C=C2; swz=0; break;
        default:W=W3; bias=b3; C=C3; swz=0; break;
    }
    const int bm = blockIdx.y*256, bn = blockIdx.x*256;
    const int tid = threadIdx.x;
    const int lane = tid & 63, g = lane >> 4, rl = lane & 15;
    const int w = tid >> 6, wr = w >> 2, wc = w & 3;

    auto STAGE = [&](int slot, int kt) {
        int k0 = kt*32;
        #pragma unroll
        for (int r2 = 0; r2 < 2; ++r2) {
            int cc = tid + 512*r2;
            int row = cc >> 2, ch = cc & 3;
            gload16(A + (size_t)(bm + row)*EE + k0 + ch*8, &SA[slot][cc*8]);
        }
        #pragma unroll
        for (int r2 = 0; r2 < 2; ++r2) {
            int cc = tid + 512*r2;
            int row = cc >> 2, ch = cc & 3;
            gload16(W + (size_t)(bn + row)*EE + k0 + ch*8, &SB[slot][cc*8]);
        }
    };

    f32x4 acc[8][4] = {};
    STAGE(0, 0); STAGE(1, 1);
    for (int t = 0; t < 32; ++t) {
        if (t < 31) asm volatile("s_waitcnt vmcnt(4)" ::: "memory");
        else        asm volatile("s_waitcnt vmcnt(0)" ::: "memory");
        __builtin_amdgcn_s_barrier();
        int cur = t % 3;
        if (t + 2 < 32) STAGE((t+2) % 3, t+2);
        const u16* SAc = SA[cur]; const u16* SBc = SB[cur];
        short8 a[8], b[4];
        #pragma unroll
        for (int i = 0; i < 8; ++i) {
            int m = wr*128 + i*16 + rl;
            a[i] = *(const short8*)&SAc[m*32 + ((g ^ ((m>>1)&3)) << 3)];
        }
        #pragma unroll
        for (int j = 0; j < 4; ++j) {
            int n = wc*64 + j*16 + rl;
            b[j] = *(const short8*)&SBc[n*32 + ((g ^ ((n>>1)&3)) << 3)];
        }
        #pragma unroll
        for (int i = 0; i < 8; ++i)
            #pragma unroll
            for (int j = 0; j < 4; ++j)
                acc[i][j] = __builtin_amdgcn_mfma_f32_16x16x32_bf16(a[i], b[j], acc[i][j], 0, 0, 0);
    }
    float bj[4];
    #pragma unroll
    for (int j = 0; j < 4; ++j) bj[j] = bias[bn + wc*64 + j*16 + rl];
    #pragma unroll
    for (int i = 0; i < 8; ++i)
      #pragma unroll
      for (int rr = 0; rr < 4; ++rr) {
        int m = bm + wr*128 + i*16 + g*4 + rr;
        #pragma unroll
        for (int j = 0; j < 4; ++j) {
            int n = bn + wc*64 + j*16 + rl;
            float v = acc[i][j][rr] + bj[j];
            int col = swz ? ((n & ~63) | ((((n>>3)&7) ^ (m&7)) << 3) | (n & 7)) : n;
            C[(size_t)m*EE + col] = f2bf(v);
        }
      }
}

// ---------------------------------------------------------------------------
// Output projection: 128x128 tile, 4 waves, same ring-3 counted-vmcnt schedule.
// ---------------------------------------------------------------------------
__global__ __launch_bounds__(256)
void gemm_out(const u16* __restrict__ A, const u16* __restrict__ W,
              const float* __restrict__ bias, float* __restrict__ C)
{
    __shared__ u16 SA[3][128*32];   // 24 KB
    __shared__ u16 SB[3][128*32];   // 24 KB
    const int bm = blockIdx.y*128, bn = blockIdx.x*128;
    const int tid = threadIdx.x;
    const int lane = tid & 63, g = lane >> 4, rl = lane & 15;
    const int w = tid >> 6, wr = w >> 1, wc = w & 1;

    auto STAGE = [&](int slot, int kt) {
        int k0 = kt*32;
        #pragma unroll
        for (int r2 = 0; r2 < 2; ++r2) {
            int cc = tid + 256*r2;
            int row = cc >> 2, ch = cc & 3;
            gload16(A + (size_t)(bm + row)*EE + k0 + ch*8, &SA[slot][cc*8]);
        }
        #pragma unroll
        for (int r2 = 0; r2 < 2; ++r2) {
            int cc = tid + 256*r2;
            int row = cc >> 2, ch = cc & 3;
            gload16(W + (size_t)(bn + row)*EE + k0 + ch*8, &SB[slot][cc*8]);
        }
    };

    f32x4 acc[4][4] = {};
    STAGE(0, 0); STAGE(1, 1);
    for (int t = 0; t < 32; ++t) {
        if (t < 31) asm volatile("s_waitcnt vmcnt(4)" ::: "memory");
        else        asm volatile("s_waitcnt vmcnt(0)" ::: "memory");
        __builtin_amdgcn_s_barrier();
        int cur = t % 3;
        if (t + 2 < 32) STAGE((t+2) % 3, t+2);
        const u16* SAc = SA[cur]; const u16* SBc = SB[cur];
        short8 a[4], b[4];
        #pragma unroll
        for (int i = 0; i < 4; ++i) {
            int m = wr*64 + i*16 + rl;
            a[i] = *(const short8*)&SAc[m*32 + ((g ^ ((m>>1)&3)) << 3)];
            int n = wc*64 + i*16 + rl;
            b[i] = *(const short8*)&SBc[n*32 + ((g ^ ((n>>1)&3)) << 3)];
        }
        #pragma unroll
        for (int i = 0; i < 4; ++i)
            #pragma unroll
            for (int j = 0; j < 4; ++j)
                acc[i][j] = __builtin_amdgcn_mfma_f32_16x16x32_bf16(a[i], b[j], acc[i][j], 0, 0, 0);
    }
    float bj[4];
    #pragma unroll
    for (int j = 0; j < 4; ++j) bj[j] = bias[bn + wc*64 + j*16 + rl];
    #pragma unroll
    for (int i = 0; i < 4; ++i)
      #pragma unroll
      for (int rr = 0; rr < 4; ++rr) {
        int m = bm + wr*64 + i*16 + g*4 + rr;
        #pragma unroll
        for (int j = 0; j < 4; ++j) {
            int n = bn + wc*64 + j*16 + rl;
            C[(size_t)m*EE + n] = acc[i][j][rr] + bj[j];
        }
      }
}

// ---------------------------------------------------------------------------
// RoPE in place on d-chunk-swizzled bf16 Q/K.
// ---------------------------------------------------------------------------
__global__ __launch_bounds__(256)
void rope_swz(u16* __restrict__ Q, u16* __restrict__ K,
              const float* __restrict__ ctab, const float* __restrict__ stab)
{
    u16* X = blockIdx.z ? K : Q;
    int ci = blockIdx.x*256 + threadIdx.x;
    int row = ci >> 7;
    int t = row & (TT-1);
    int c = ci & 127, h = c >> 3, p = c & 7;
    int d0 = (p ^ (t & 7)) << 3;
    u16* ptr = X + (size_t)row*EE + h*HDD + p*8;
    short8 xv = *(short8*)ptr;
    u16* xu = (u16*)&xv;
    const float* cr = ctab + t*32;
    const float* sr = stab + t*32;
    short8 ov; u16* o = (u16*)&ov;
    #pragma unroll
    for (int q = 0; q < 4; ++q) {
        int j0 = d0 + 2*q;
        float xe = bf2f(xu[2*q]), xo = bf2f(xu[2*q+1]);
        float c0 = cr[j0 & 31],     s0 = sr[j0 & 31];
        float c1 = cr[(j0+1) & 31], s1 = sr[(j0+1) & 31];
        o[2*q]   = f2bf(xe*c0 - xo*s0);
        o[2*q+1] = f2bf(xo*c1 + xe*s1);
    }
    *(short8*)ptr = ov;
}

// ---------------------------------------------------------------------------
// V -> VT [b][h][d][t] with t-chunk swizzle (pos p holds logical p^(d&7)).
// ---------------------------------------------------------------------------
__global__ __launch_bounds__(256)
void transV(const u16* __restrict__ V, u16* __restrict__ VT)
{
    __shared__ u16 ts[64*64];
    int t0 = blockIdx.x * 64, h = blockIdx.y, b = blockIdx.z;
    int tid = threadIdx.x;
    #pragma unroll
    for (int rr = 0; rr < 2; ++rr) {
        int cc = tid + rr*256;
        int r = cc >> 3, c = cc & 7;
        short8 v = *(const short8*)(V + (size_t)(b*TT + t0 + r)*EE + h*HDD + c*8);
        *(short8*)&ts[r*64 + ((c ^ (r & 7)) << 3)] = v;
    }
    __syncthreads();
    #pragma unroll
    for (int rr = 0; rr < 2; ++rr) {
        int oc = tid + rr*256;
        int d = oc & 63, tp = oc >> 6;
        short8 ov; u16* o = (u16*)&ov;
        #pragma unroll
        for (int e = 0; e < 8; ++e) {
            int t = tp*8 + e;
            o[e] = ts[t*64 + (((d>>3) ^ (t & 7)) << 3) + (d & 7)];
        }
        int ptp = tp ^ (d & 7);
        *(short8*)(VT + ((size_t)((b*HH + h)*HDD + d))*TT + t0 + ptp*8) = ov;
    }
}

// ---------------------------------------------------------------------------
// K (d-chunk-swizzled, post-RoPE) -> KT [b][h][d][t], scaled by gamma^(t&63),
// with the same t-chunk swizzle as VT.
// ---------------------------------------------------------------------------
__global__ __launch_bounds__(256)
void transK(const u16* __restrict__ K, u16* __restrict__ KT)
{
    __shared__ u16 ts[64*64];
    int t0 = blockIdx.x * 64, h = blockIdx.y, b = blockIdx.z;
    int tid = threadIdx.x;
    const float l2g = log2f(1.f - exp2f(-5.f - (float)h));
    #pragma unroll
    for (int rr = 0; rr < 2; ++rr) {
        int cc = tid + rr*256;
        int r = cc >> 3, c = cc & 7;           // c = STORED chunk = logical^(r&7)
        short8 v = *(const short8*)(K + (size_t)(b*TT + t0 + r)*EE + h*HDD + c*8);
        *(short8*)&ts[r*64 + (c << 3)] = v;    // lands at logical^(r&7) — transV convention
    }
    __syncthreads();
    #pragma unroll
    for (int rr = 0; rr < 2; ++rr) {
        int oc = tid + rr*256;
        int d = oc & 63, tp = oc >> 6;
        short8 ov; u16* o = (u16*)&ov;
        #pragma unroll
        for (int e = 0; e < 8; ++e) {
            int t = tp*8 + e;
            float val = bf2f(ts[t*64 + (((d>>3) ^ (t & 7)) << 3) + (d & 7)]);
            o[e] = f2bf(val * exp2f(l2g * (float)t));
        }
        int ptp = tp ^ (d & 7);
        *(short8*)(KT + ((size_t)((b*HH + h)*HDD + d))*TT + t0 + ptp*8) = ov;
    }
}

// ---------------------------------------------------------------------------
// Per-chunk state: Tt[c][d2][d1] = sum_n V[n][d2] * K[n][d1]*gamma^n̂  (f32).
// ---------------------------------------------------------------------------
__global__ __launch_bounds__(256)
void chunk_state(const u16* __restrict__ KT, const u16* __restrict__ VT,
                 float* __restrict__ Tb)
{
    __shared__ u16 Ks[64*64], Vs[64*64];
    const int tid = threadIdx.x, w = tid >> 6, lane = tid & 63;
    const int g = lane >> 4, rl = lane & 15;
    const int c = blockIdx.x, h = blockIdx.y, b = blockIdx.z;
    const int t0 = c*64;
    const size_t rowb = (size_t)((b*HH + h)*HDD);
    {
        int cc = tid, r = cc >> 3, ch = cc & 7;
        gload16(KT + (rowb + r)*TT + t0 + ch*8, &Ks[cc*8]);
        gload16(VT + (rowb + r)*TT + t0 + ch*8, &Vs[cc*8]);
        cc = tid + 256; r = cc >> 3; ch = cc & 7;
        gload16(KT + (rowb + r)*TT + t0 + ch*8, &Ks[cc*8]);
        gload16(VT + (rowb + r)*TT + t0 + ch*8, &Vs[cc*8]);
    }
    __syncthreads();
    int d2r = w*16 + rl;
    short8 af0 = *(const short8*)&Vs[d2r*64 + ((g ^ (d2r & 7)) << 3)];
    short8 af1 = *(const short8*)&Vs[d2r*64 + (((4+g) ^ (d2r & 7)) << 3)];
    f32x4 acc[4] = {};
    #pragma unroll
    for (int j = 0; j < 4; ++j) {
        int d1r = j*16 + rl;
        short8 b0 = *(const short8*)&Ks[d1r*64 + ((g ^ (d1r & 7)) << 3)];
        short8 b1 = *(const short8*)&Ks[d1r*64 + (((4+g) ^ (d1r & 7)) << 3)];
        acc[j] = __builtin_amdgcn_mfma_f32_16x16x32_bf16(af0, b0, acc[j], 0, 0, 0);
        acc[j] = __builtin_amdgcn_mfma_f32_16x16x32_bf16(af1, b1, acc[j], 0, 0, 0);
    }
    float* tb = Tb + ((size_t)((b*HH + h)*NC + c))*4096;
    #pragma unroll
    for (int j = 0; j < 4; ++j)
        #pragma unroll
        for (int rr = 0; rr < 4; ++rr)
            tb[(w*16 + g*4 + rr)*64 + j*16 + rl] = acc[j][rr];
}

// ---------------------------------------------------------------------------
// Suffix scan over chunks: Z_c = T_{c+1} + g64*Z_{c+1}, Z_31 = 0.
// ---------------------------------------------------------------------------
__global__ __launch_bounds__(256)
void suffix_scan(const float* __restrict__ Tb, u16* __restrict__ Zb)
{
    __shared__ float lds[NC*512];     // 64 KB
    const int q = blockIdx.x & 7;
    const int h = (blockIdx.x >> 3) & 15;
    const int b = blockIdx.x >> 7;
    const float l2g = log2f(1.f - exp2f(-5.f - (float)h));
    const float g64 = exp2f(l2g * 64.f);
    const float* tb = Tb + ((size_t)((b*HH + h)*NC))*4096 + q*512;
    u16* zb = Zb + ((size_t)((b*HH + h)*NC))*4096;
    const int tid = threadIdx.x;
    #pragma unroll
    for (int k = 0; k < 16; ++k) {
        int i4 = tid + k*256;
        int c = i4 >> 7, r = i4 & 127;
        *(float4*)&lds[c*512 + r*4] = *(const float4*)(tb + (size_t)c*4096 + r*4);
    }
    __syncthreads();
    int e0 = tid*2;
    int d2l = e0 >> 6, d1 = e0 & 63;
    int d2 = q*8 + d2l;
    int pos = d2*64 + (((d1>>3) ^ (d2 & 7)) << 3) + (d1 & 7);
    *(u32*)(zb + (size_t)31*4096 + pos) = 0u;
    float z0 = 0.f, z1 = 0.f;
    for (int c = 30; c >= 0; --c) {
        z0 = lds[(c+1)*512 + e0]     + g64*z0;
        z1 = lds[(c+1)*512 + e0 + 1] + g64*z1;
        u32 pk = (u32)f2bf(z0) | ((u32)f2bf(z1) << 16);
        *(u32*)(zb + (size_t)c*4096 + pos) = pk;
    }
}

// ---------------------------------------------------------------------------
// Output: per chunk c:
//   R = (QK^T/8 ∘ mask_diag) V  +  0.125*gamma^(64-m̂) * Q · Z_c
// ---------------------------------------------------------------------------
__global__ __launch_bounds__(256)
void ret_out(const u16* __restrict__ Q, const u16* __restrict__ K,
             const u16* __restrict__ VT, const u16* __restrict__ Zb,
             float* __restrict__ R)
{
    __shared__ u16 Qs[64*64], Ks[64*64], Vs[64*64], Zs[64*64], Ss[64*64];
    const int tid = threadIdx.x, w = tid >> 6, lane = tid & 63;
    const int g = lane >> 4, rl = lane & 15;
    const int c = blockIdx.x, h = blockIdx.y, b = blockIdx.z;
    const int m0 = c*64;
    const float l2g = log2f(1.f - exp2f(-5.f - (float)h));
    const size_t vrow = (size_t)((b*HH + h)*HDD);
    const u16* zc = Zb + ((size_t)((b*HH + h)*NC + c))*4096;
    {
        int cc = tid, r = cc >> 3, ch = cc & 7;
        gload16(Q  + (size_t)(b*TT + m0 + r)*EE + h*HDD + ch*8, &Qs[cc*8]);
        gload16(K  + (size_t)(b*TT + m0 + r)*EE + h*HDD + ch*8, &Ks[cc*8]);
        gload16(VT + (vrow + r)*TT + m0 + ch*8, &Vs[cc*8]);
        gload16(zc + cc*8, &Zs[cc*8]);
        cc = tid + 256; r = cc >> 3; ch = cc & 7;
        gload16(Q  + (size_t)(b*TT + m0 + r)*EE + h*HDD + ch*8, &Qs[cc*8]);
        gload16(K  + (size_t)(b*TT + m0 + r)*EE + h*HDD + ch*8, &Ks[cc*8]);
        gload16(VT + (vrow + r)*TT + m0 + ch*8, &Vs[cc*8]);
        gload16(zc + cc*8, &Zs[cc*8]);
    }
    __syncthreads();
    const int mr = w*16 + rl;
    short8 qf[2];
    qf[0] = *(const short8*)&Qs[mr*64 + ((g ^ (rl & 7)) << 3)];
    qf[1] = *(const short8*)&Qs[mr*64 + (((4+g) ^ (rl & 7)) << 3)];
    f32x4 sacc[4] = {};
    #pragma unroll
    for (int j = 0; j < 4; ++j) {
        int n = j*16 + rl;
        short8 k0 = *(const short8*)&Ks[n*64 + ((g ^ (n & 7)) << 3)];
        short8 k1 = *(const short8*)&Ks[n*64 + (((4+g) ^ (n & 7)) << 3)];
        sacc[j] = __builtin_amdgcn_mfma_f32_16x16x32_bf16(qf[0], k0, sacc[j], 0, 0, 0);
        sacc[j] = __builtin_amdgcn_mfma_f32_16x16x32_bf16(qf[1], k1, sacc[j], 0, 0, 0);
    }
    float pn[4], pmv[4];
    #pragma unroll
    for (int j = 0; j < 4; ++j) pn[j] = exp2f(l2g * (float)(j*16 + rl));
    #pragma unroll
    for (int rr = 0; rr < 4; ++rr) pmv[rr] = exp2f(-l2g * (float)(w*16 + g*4 + rr));
    #pragma unroll
    for (int j = 0; j < 4; ++j) {
        int nl = j*16 + rl;
        #pragma unroll
        for (int rr = 0; rr < 4; ++rr) {
            int ml = w*16 + g*4 + rr;
            float wgt = (nl >= ml) ? 0.125f * pn[j] * pmv[rr] : 0.f;
            Ss[ml*64 + (((nl>>3) ^ (ml & 7)) << 3) + (nl & 7)] = f2bf(sacc[j][rr] * wgt);
        }
    }
    asm volatile("s_waitcnt lgkmcnt(0)" ::: "memory");  // wave-private S rows
    f32x4 oacc[4] = {}, zacc[4] = {};
    #pragma unroll
    for (int s = 0; s < 2; ++s) {
        short8 sf = *(const short8*)&Ss[mr*64 + (((s*4 + g) ^ (rl & 7)) << 3)];
        #pragma unroll
        for (int j = 0; j < 4; ++j) {
            int d = j*16 + rl;
            short8 vf = *(const short8*)&Vs[d*64 + (((s*4 + g) ^ (d & 7)) << 3)];
            oacc[j] = __builtin_amdgcn_mfma_f32_16x16x32_bf16(sf, vf, oacc[j], 0, 0, 0);
            short8 zf = *(const short8*)&Zs[d*64 + (((s*4 + g) ^ (d & 7)) << 3)];
            zacc[j] = __builtin_amdgcn_mfma_f32_16x16x32_bf16(qf[s], zf, zacc[j], 0, 0, 0);
        }
    }
    const float g64 = exp2f(l2g * 64.f);
    #pragma unroll
    for (int j = 0; j < 4; ++j)
        #pragma unroll
        for (int rr = 0; rr < 4; ++rr) {
            int m_g = m0 + w*16 + g*4 + rr;
            float rs = 0.125f * g64 * pmv[rr];
            R[(size_t)(b*TT + m_g)*EE + h*HDD + j*16 + rl] = oacc[j][rr] + rs*zacc[j][rr];
        }
}

// ---------------------------------------------------------------------------
__global__ __launch_bounds__(256)
void gn_partial(const float* __restrict__ R, float* __restrict__ part)
{
    int bid = blockIdx.x;
    int bh = bid >> 4, seg = bid & 15;
    int b = bh >> 4, h = bh & 15;
    const float* base = R + (size_t)(b*TT + seg*128)*EE + h*HDD;
    float s = 0.f, sq = 0.f;
    #pragma unroll
    for (int k = 0; k < 8; ++k) {
        int i4 = threadIdx.x + 256*k;
        int t = i4 >> 4, dq = i4 & 15;
        float4 v = *(const float4*)(base + (size_t)t*EE + dq*4);
        s  += v.x + v.y + v.z + v.w;
        sq += v.x*v.x + v.y*v.y + v.z*v.z + v.w*v.w;
    }
    #pragma unroll
    for (int off = 32; off; off >>= 1) { s += __shfl_down(s, off, 64); sq += __shfl_down(sq, off, 64); }
    __shared__ float ls[4], lq[4];
    int lane = threadIdx.x & 63, wv = threadIdx.x >> 6;
    if (lane == 0) { ls[wv] = s; lq[wv] = sq; }
    __syncthreads();
    if (threadIdx.x == 0) {
        part[2*bid]   = ls[0]+ls[1]+ls[2]+ls[3];
        part[2*bid+1] = lq[0]+lq[1]+lq[2]+lq[3];
    }
}

__global__ void gn_finalize(const float* __restrict__ part, float* __restrict__ stats)
{
    int bh = threadIdx.x;
    if (bh < 32) {
        float s = 0.f, sq = 0.f;
        #pragma unroll
        for (int k = 0; k < 16; ++k) { s += part[2*(bh*16+k)]; sq += part[2*(bh*16+k)+1]; }
        const float inv = 1.f / (float)(TT*HDD);
        float mu = s * inv;
        float var = sq * inv - mu*mu;
        stats[2*bh]   = mu;
        stats[2*bh+1] = rsqrtf(var + 1e-5f);
    }
}

// ---------------------------------------------------------------------------
__global__ __launch_bounds__(256)
void zgate(const u16* __restrict__ G, const float* __restrict__ R,
           const float* __restrict__ stats, const float* __restrict__ gw,
           const float* __restrict__ gb, u16* __restrict__ Z)
{
    int ci = blockIdx.x*256 + threadIdx.x;
    int row = ci >> 7;
    int c = ci & 127;
    int e0 = c*8;
    int b = row >> 11;
    int bh = b*HH + (e0 >> 6);
    float mu = stats[2*bh], rs = stats[2*bh+1];
    short8 gv = *(const short8*)(G + (size_t)row*EE + e0);
    const u16* gu = (const u16*)&gv;
    const float* rp = R + (size_t)row*EE + e0;
    float4 r0 = *(const float4*)rp, r1 = *(const float4*)(rp+4);
    float rr[8] = {r0.x,r0.y,r0.z,r0.w,r1.x,r1.y,r1.z,r1.w};
    short8 ov; u16* o = (u16*)&ov;
    #pragma unroll
    for (int q = 0; q < 8; ++q) {
        float gvf = bf2f(gu[q]);
        float gate = gvf / (1.f + __expf(-gvf));
        float nv = (rr[q] - mu)*rs*gw[e0+q] + gb[e0+q];
        o[q] = f2bf(gate*nv);
    }
    int pc = (c & ~3) | ((c & 3) ^ ((row >> 1) & 3));
    *(short8*)(Z + (size_t)row*EE + pc*8) = ov;
}

// ---------------------------------------------------------------------------
extern "C" void kernel_launch(void* const* d_in, const int* in_sizes, int n_in,
                              void* d_out, int out_size, void* d_ws, size_t ws_size,
                              hipStream_t stream)
{
    const float* x  = (const float*)d_in[0];
    const float* Wq = (const float*)d_in[1];
    const float* bq = (const float*)d_in[2];
    const float* Wk = (const float*)d_in[3];
    const float* bk = (const float*)d_in[4];
    const float* Wv = (const float*)d_in[5];
    const float* bv = (const float*)d_in[6];
    const float* Wg = (const float*)d_in[7];
    const float* bg = (const float*)d_in[8];
    const float* Wo = (const float*)d_in[9];
    const float* bo = (const float*)d_in[10];
    const float* gw = (const float*)d_in[11];
    const float* gb = (const float*)d_in[12];
    float* out = (float*)d_out;

    char* p = (char*)d_ws;
    u16* xb  = (u16*)p;              p += (size_t)8<<20;   // x bf16 -> Zbuf -> ZGb
    u16* Wqb = (u16*)p;              p += (size_t)2<<20;
    u16* Wkb = (u16*)p;              p += (size_t)2<<20;
    u16* Wvb = (u16*)p;              p += (size_t)2<<20;
    u16* Wgb = (u16*)p;              p += (size_t)2<<20;
    u16* Wob = (u16*)p;              p += (size_t)2<<20;
    u16* Qb  = (u16*)p;              p += (size_t)8<<20;
    u16* Kb  = (u16*)p;              p += (size_t)8<<20;
    u16* Vb  = (u16*)p;              p += (size_t)8<<20;
    u16* Gb  = (u16*)p;              p += (size_t)8<<20;
    u16* VTb = (u16*)p;              p += (size_t)8<<20;
    u16* KTb = (u16*)p;              p += (size_t)8<<20;
    float* TbRb  = (float*)p;        p += (size_t)16<<20;  // Tb (chunk states) -> Rb
    float* part  = (float*)p;        p += 4096;
    float* stats = (float*)p;        p += 256;
    float* ctab  = (float*)p;        p += (size_t)65536*4;
    float* stab  = (float*)p;        p += (size_t)65536*4;
    u16* Zbuf = xb;                  // x dead after QKVG
    float* Tb = TbRb;
    float* Rb = TbRb;                // ret_out writes after scan reads
    u16* ZGb = xb;                   // zgate output (after ret_out)

    cvt_swz<<<dim3(2048,1,6), 256, 0, stream>>>(x, Wq, Wk, Wv, Wg, Wo,
                                                xb, Wqb, Wkb, Wvb, Wgb, Wob);
    trig_tab<<<256, 256, 0, stream>>>(ctab, stab);
    gemm_qkvg<<<dim3(4,16,4), 512, 0, stream>>>(xb, Wqb, Wkb, Wvb, Wgb,
                                                bq, bk, bv, bg, Qb, Kb, Vb, Gb);
    rope_swz<<<dim3(2048,1,2), 256, 0, stream>>>(Qb, Kb, ctab, stab);
    transV<<<dim3(32,16,2), 256, 0, stream>>>(Vb, VTb);
    transK<<<dim3(32,16,2), 256, 0, stream>>>(Kb, KTb);
    chunk_state<<<dim3(32,16,2), 256, 0, stream>>>(KTb, VTb, Tb);
    suffix_scan<<<256, 256, 0, stream>>>(Tb, Zbuf);
    ret_out<<<dim3(32,16,2), 256, 0, stream>>>(Qb, Kb, VTb, Zbuf, Rb);
    gn_partial<<<512, 256, 0, stream>>>(Rb, part);
    gn_finalize<<<1, 64, 0, stream>>>(part, stats);
    zgate<<<2048, 256, 0, stream>>>(Gb, Rb, stats, gw, gb, ZGb);
    gemm_out<<<dim3(8,32,1), 256, 0, stream>>>(ZGb, Wob, bo, out);
}

// Round 8
// 223.621 us; speedup vs baseline: 1.0327x; 1.0327x over previous
//
#include <hip/hip_runtime.h>
#include <math.h>

typedef unsigned short u16;
typedef unsigned int u32;
typedef __attribute__((ext_vector_type(8))) short short8;
typedef __attribute__((ext_vector_type(4))) float f32x4;

#define BB 2
#define TT 2048
#define EE 1024
#define HH 16
#define HDD 64
#define NC 32
#define CS 64

__device__ __forceinline__ float bf2f(u16 u){ union{unsigned i; float f;} v; v.i=((unsigned)u)<<16; return v.f; }
__device__ __forceinline__ u16 f2bf(float f){ union{float f; unsigned i;} v; v.f=f; return (u16)((v.i + 0x7fffu + ((v.i>>16)&1u))>>16); }

__device__ __forceinline__ void gload16(const void* g, void* l){
    __builtin_amdgcn_global_load_lds((const __attribute__((address_space(1))) void*)g,
                                     (__attribute__((address_space(3))) void*)l, 16, 0, 0);
}

// ---------------------------------------------------------------------------
// f32 -> bf16 conversion with GEMM chunk swizzle baked into global layout.
// z=0..4 (x, Wq,Wk,Wv,Wg): NEW swizzle (chunk j -> j^(row&7)) for 8-phase GEMM.
// z=5 (Wo): OLD swizzle ((c&3)^((r>>1)&3)) for the ring-3 gemm_out.
// z=6: RoPE trig table.
// ---------------------------------------------------------------------------
__global__ __launch_bounds__(256)
void cvt_swz(const float* __restrict__ s0, const float* __restrict__ s1,
             const float* __restrict__ s2, const float* __restrict__ s3,
             const float* __restrict__ s4, const float* __restrict__ s5,
             u16* __restrict__ d0, u16* __restrict__ d1, u16* __restrict__ d2,
             u16* __restrict__ d3, u16* __restrict__ d4, u16* __restrict__ d5,
             float* __restrict__ ctab, float* __restrict__ stab)
{
    if (blockIdx.z == 6) {
        if (blockIdx.x >= 256) return;
        int idx = blockIdx.x*256 + threadIdx.x;   // 65536
        int t = idx >> 5, f = idx & 31;
        float ang = (float)t * exp2f(-(float)f * (13.287712379549449f/32.f));
        ctab[idx] = cosf(ang);
        stab[idx] = sinf(ang);
        return;
    }
    const float* S; u16* D; int nch; int oldswz = 0;
    switch (blockIdx.z) {
        case 0: S=s0; D=d0; nch=4096*128; break;
        case 1: S=s1; D=d1; nch=1024*128; break;
        case 2: S=s2; D=d2; nch=1024*128; break;
        case 3: S=s3; D=d3; nch=1024*128; break;
        case 4: S=s4; D=d4; nch=1024*128; break;
        default:S=s5; D=d5; nch=1024*128; oldswz=1; break;
    }
    int ci = blockIdx.x*256 + threadIdx.x;
    if (ci >= nch) return;
    int r = ci >> 7, c = ci & 127;
    int pc = oldswz ? ((c & ~3) | ((c & 3) ^ ((r >> 1) & 3)))
                    : ((c & ~7) | ((c & 7) ^ (r & 7)));
    const float4* sp = (const float4*)(S + (size_t)r*EE + c*8);
    float4 f0 = sp[0], f1 = sp[1];
    short8 ov; u16* o = (u16*)&ov;
    o[0]=f2bf(f0.x); o[1]=f2bf(f0.y); o[2]=f2bf(f0.z); o[3]=f2bf(f0.w);
    o[4]=f2bf(f1.x); o[5]=f2bf(f1.y); o[6]=f2bf(f1.z); o[7]=f2bf(f1.w);
    *(short8*)(D + (size_t)r*EE + pc*8) = ov;
}

// ---------------------------------------------------------------------------
// Fused QKVG projections: 256x256 tile, BK=64, 8 waves (2M x 4N), 8-phase
// schedule, double-buffered 128KB LDS, counted vmcnt(4) at phases 4/8 only.
// Phase: {ds_read frags | stage 1 half-tile} bar lgkm0 prio1 16xMFMA prio0 bar.
// Staging order (by LDS region release time):
//   ph1: A(2i+1)h0  ph2: A(2i+1)h1  ph3: B(2i+2)h0  ph4: B(2i+2)h1 +vm(4)
//   ph5: A(2i+2)h0  ph6: A(2i+2)h1  ph7: B(2i+3)h0  ph8: B(2i+3)h1 +vm(4)
// ---------------------------------------------------------------------------
__global__ __launch_bounds__(512, 2)
void gemm_qkvg(const u16* __restrict__ A,
               const u16* __restrict__ W0, const u16* __restrict__ W1,
               const u16* __restrict__ W2, const u16* __restrict__ W3,
               const float* __restrict__ b0, const float* __restrict__ b1,
               const float* __restrict__ b2, const float* __restrict__ b3,
               u16* __restrict__ C0, u16* __restrict__ C1,
               u16* __restrict__ C2, u16* __restrict__ C3)
{
    __shared__ u16 AS[2][16384];   // [buf][half(128 rows)x64]  64 KB
    __shared__ u16 BS[2][16384];   // 64 KB
    const u16* W; const float* bias; u16* C; int swz;
    switch (blockIdx.z) {
        case 0: W=W0; bias=b0; C=C0; swz=1; break;
        case 1: W=W1; bias=b1; C=C1; swz=1; break;
        case 2: W=W2; bias=b2; C=C2; swz=0; break;
        default:W=W3; bias=b3; C=C3; swz=0; break;
    }
    const int bm = blockIdx.y*256, bn = blockIdx.x*256;
    const int tid = threadIdx.x;
    const int lane = tid & 63, g = lane >> 4, rl = lane & 15;
    const int w = tid >> 6, wr = w >> 2, wc = w & 3;

    auto stage_half = [&](int isB, int kt, int half){
        const u16* src = isB ? W : A;
        int bb = isB ? bn : bm;
        u16* dst = (isB ? &BS[kt&1][0] : &AS[kt&1][0]) + half*8192;
        #pragma unroll
        for (int r2 = 0; r2 < 2; ++r2) {
            int cc = tid + 512*r2;          // 0..1023
            int hr = cc >> 3, pcc = cc & 7;
            gload16(src + (size_t)(bb + half*128 + hr)*EE + kt*64 + pcc*8, dst + cc*8);
        }
    };
    short8 a[8], bf0[4], bf1[4];
    auto read_a = [&](int bi, int Mh){
        const u16* base = &AS[bi][wr*8192];
        #pragma unroll
        for (int mb = 0; mb < 4; ++mb)
          #pragma unroll
          for (int kh = 0; kh < 2; ++kh) {
            int hr = Mh*64 + mb*16 + rl;
            a[mb*2+kh] = *(const short8*)&base[hr*64 + (((kh*4+g) ^ (hr&7)) << 3)];
          }
    };
    auto read_b = [&](short8 (&bf)[4], int bi, int Nh){
        #pragma unroll
        for (int nb = 0; nb < 2; ++nb)
          #pragma unroll
          for (int kh = 0; kh < 2; ++kh) {
            int nr = wc*64 + Nh*32 + nb*16 + rl;
            int half = nr >> 7, hr = nr & 127;
            bf[nb*2+kh] = *(const short8*)&BS[bi][half*8192 + hr*64 + (((kh*4+g) ^ (hr&7)) << 3)];
          }
    };
    f32x4 acc[8][4] = {};
    auto mfma_q = [&](short8 (&bf)[4], int Mh, int Nh){
        __builtin_amdgcn_s_setprio(1);
        #pragma unroll
        for (int mb = 0; mb < 4; ++mb)
          #pragma unroll
          for (int nb = 0; nb < 2; ++nb)
            #pragma unroll
            for (int kh = 0; kh < 2; ++kh)
              acc[Mh*4+mb][Nh*2+nb] = __builtin_amdgcn_mfma_f32_16x16x32_bf16(
                  a[mb*2+kh], bf[nb*2+kh], acc[Mh*4+mb][Nh*2+nb], 0, 0, 0);
        __builtin_amdgcn_s_setprio(0);
    };
    #define BAR()    __builtin_amdgcn_s_barrier()
    #define LGKM0()  { asm volatile("s_waitcnt lgkmcnt(0)" ::: "memory"); __builtin_amdgcn_sched_barrier(0); }
    #define VM4()    asm volatile("s_waitcnt vmcnt(4)" ::: "memory")

    // prologue: tile0 A+B, tile1 B; confirm tile0 landed.
    stage_half(0,0,0); stage_half(0,0,1); stage_half(1,0,0); stage_half(1,0,1);
    stage_half(1,1,0); stage_half(1,1,1);
    VM4(); BAR();

    for (int i = 0; i < 7; ++i) {
        int k1 = 2*i+1, k2 = 2*i+2, k3 = 2*i+3;
        // ph1
        read_a(0,0); read_b(bf0,0,0); stage_half(0,k1,0);
        BAR(); LGKM0(); mfma_q(bf0,0,0); BAR();
        // ph2
        read_b(bf1,0,1); stage_half(0,k1,1);
        BAR(); LGKM0(); mfma_q(bf1,0,1); BAR();
        // ph3
        read_a(0,1); stage_half(1,k2,0);
        BAR(); LGKM0(); mfma_q(bf0,1,0); BAR();
        // ph4
        stage_half(1,k2,1); VM4();
        BAR(); mfma_q(bf1,1,1); BAR();
        // ph5
        read_a(1,0); read_b(bf0,1,0); stage_half(0,k2,0);
        BAR(); LGKM0(); mfma_q(bf0,0,0); BAR();
        // ph6
        read_b(bf1,1,1); stage_half(0,k2,1);
        BAR(); LGKM0(); mfma_q(bf1,0,1); BAR();
        // ph7
        read_a(1,1); stage_half(1,k3,0);
        BAR(); LGKM0(); mfma_q(bf0,1,0); BAR();
        // ph8
        stage_half(1,k3,1); VM4();
        BAR(); mfma_q(bf1,1,1); BAR();
    }
    // epilogue: tiles 14,15; stage only A(15); drain mid-way.
    read_a(0,0); read_b(bf0,0,0); stage_half(0,15,0);
    BAR(); LGKM0(); mfma_q(bf0,0,0); BAR();
    read_b(bf1,0,1); stage_half(0,15,1);
    BAR(); LGKM0(); mfma_q(bf1,0,1); BAR();
    read_a(0,1);
    BAR(); LGKM0(); mfma_q(bf0,1,0); BAR();
    asm volatile("s_waitcnt vmcnt(0)" ::: "memory");
    BAR(); mfma_q(bf1,1,1); BAR();
    read_a(1,0); read_b(bf0,1,0);
    BAR(); LGKM0(); mfma_q(bf0,0,0); BAR();
    read_b(bf1,1,1);
    BAR(); LGKM0(); mfma_q(bf1,0,1); BAR();
    read_a(1,1);
    BAR(); LGKM0(); mfma_q(bf0,1,0); BAR();
    mfma_q(bf1,1,1);
    #undef BAR
    #undef LGKM0
    #undef VM4

    float bj[4];
    #pragma unroll
    for (int j = 0; j < 4; ++j) bj[j] = bias[bn + wc*64 + j*16 + rl];
    #pragma unroll
    for (int i = 0; i < 8; ++i)
      #pragma unroll
      for (int rr = 0; rr < 4; ++rr) {
        int m = bm + wr*128 + i*16 + g*4 + rr;
        #pragma unroll
        for (int j = 0; j < 4; ++j) {
            int n = bn + wc*64 + j*16 + rl;
            float v = acc[i][j][rr] + bj[j];
            int col = swz ? ((n & ~63) | ((((n>>3)&7) ^ (m&7)) << 3) | (n & 7)) : n;
            C[(size_t)m*EE + col] = f2bf(v);
        }
      }
}

// ---------------------------------------------------------------------------
// Output projection: 128x128 tile, 4 waves, ring-3 counted-vmcnt schedule.
// A (zgate output) and Wo use the OLD chunk swizzle.
// ---------------------------------------------------------------------------
__global__ __launch_bounds__(256)
void gemm_out(const u16* __restrict__ A, const u16* __restrict__ W,
              const float* __restrict__ bias, float* __restrict__ C)
{
    __shared__ u16 SA[3][128*32];
    __shared__ u16 SB[3][128*32];
    const int bm = blockIdx.y*128, bn = blockIdx.x*128;
    const int tid = threadIdx.x;
    const int lane = tid & 63, g = lane >> 4, rl = lane & 15;
    const int w = tid >> 6, wr = w >> 1, wc = w & 1;

    auto STAGE = [&](int slot, int kt) {
        int k0 = kt*32;
        #pragma unroll
        for (int r2 = 0; r2 < 2; ++r2) {
            int cc = tid + 256*r2;
            int row = cc >> 2, ch = cc & 3;
            gload16(A + (size_t)(bm + row)*EE + k0 + ch*8, &SA[slot][cc*8]);
        }
        #pragma unroll
        for (int r2 = 0; r2 < 2; ++r2) {
            int cc = tid + 256*r2;
            int row = cc >> 2, ch = cc & 3;
            gload16(W + (size_t)(bn + row)*EE + k0 + ch*8, &SB[slot][cc*8]);
        }
    };

    f32x4 acc[4][4] = {};
    STAGE(0, 0); STAGE(1, 1);
    for (int t = 0; t < 32; ++t) {
        if (t < 31) asm volatile("s_waitcnt vmcnt(4)" ::: "memory");
        else        asm volatile("s_waitcnt vmcnt(0)" ::: "memory");
        __builtin_amdgcn_s_barrier();
        int cur = t % 3;
        if (t + 2 < 32) STAGE((t+2) % 3, t+2);
        const u16* SAc = SA[cur]; const u16* SBc = SB[cur];
        short8 a[4], b[4];
        #pragma unroll
        for (int i = 0; i < 4; ++i) {
            int m = wr*64 + i*16 + rl;
            a[i] = *(const short8*)&SAc[m*32 + ((g ^ ((m>>1)&3)) << 3)];
            int n = wc*64 + i*16 + rl;
            b[i] = *(const short8*)&SBc[n*32 + ((g ^ ((n>>1)&3)) << 3)];
        }
        #pragma unroll
        for (int i = 0; i < 4; ++i)
            #pragma unroll
            for (int j = 0; j < 4; ++j)
                acc[i][j] = __builtin_amdgcn_mfma_f32_16x16x32_bf16(a[i], b[j], acc[i][j], 0, 0, 0);
    }
    float bj[4];
    #pragma unroll
    for (int j = 0; j < 4; ++j) bj[j] = bias[bn + wc*64 + j*16 + rl];
    #pragma unroll
    for (int i = 0; i < 4; ++i)
      #pragma unroll
      for (int rr = 0; rr < 4; ++rr) {
        int m = bm + wr*64 + i*16 + g*4 + rr;
        #pragma unroll
        for (int j = 0; j < 4; ++j) {
            int n = bn + wc*64 + j*16 + rl;
            C[(size_t)m*EE + n] = acc[i][j][rr] + bj[j];
        }
      }
}

// ---------------------------------------------------------------------------
// RoPE in place on d-chunk-swizzled bf16 Q/K.
// ---------------------------------------------------------------------------
__global__ __launch_bounds__(256)
void rope_swz(u16* __restrict__ Q, u16* __restrict__ K,
              const float* __restrict__ ctab, const float* __restrict__ stab)
{
    u16* X = blockIdx.z ? K : Q;
    int ci = blockIdx.x*256 + threadIdx.x;
    int row = ci >> 7;
    int t = row & (TT-1);
    int c = ci & 127, h = c >> 3, p = c & 7;
    int d0 = (p ^ (t & 7)) << 3;
    u16* ptr = X + (size_t)row*EE + h*HDD + p*8;
    short8 xv = *(short8*)ptr;
    u16* xu = (u16*)&xv;
    const float* cr = ctab + t*32;
    const float* sr = stab + t*32;
    short8 ov; u16* o = (u16*)&ov;
    #pragma unroll
    for (int q = 0; q < 4; ++q) {
        int j0 = d0 + 2*q;
        float xe = bf2f(xu[2*q]), xo = bf2f(xu[2*q+1]);
        float c0 = cr[j0 & 31],     s0 = sr[j0 & 31];
        float c1 = cr[(j0+1) & 31], s1 = sr[(j0+1) & 31];
        o[2*q]   = f2bf(xe*c0 - xo*s0);
        o[2*q+1] = f2bf(xo*c1 + xe*s1);
    }
    *(short8*)ptr = ov;
}

// ---------------------------------------------------------------------------
// Merged transV/transK: z in [0,4): b = z&1, kind = z>>1 (0=V,1=K).
// Output [b][h][d][t] with t-chunk swizzle (pos p holds logical p^(d&7)).
// K input is d-chunk swizzled; gamma^(t mod 64) baked into KT.
// ---------------------------------------------------------------------------
__global__ __launch_bounds__(256)
void transKV(const u16* __restrict__ V, const u16* __restrict__ K,
             u16* __restrict__ VT, u16* __restrict__ KT)
{
    __shared__ u16 ts[64*64];
    int t0 = blockIdx.x * 64, h = blockIdx.y;
    int b = blockIdx.z & 1, kind = blockIdx.z >> 1;
    const u16* src = kind ? K : V;
    u16* dst = kind ? KT : VT;
    int tid = threadIdx.x;
    const float l2g = log2f(1.f - exp2f(-5.f - (float)h));
    #pragma unroll
    for (int rr = 0; rr < 2; ++rr) {
        int cc = tid + rr*256;
        int r = cc >> 3, c = cc & 7;
        short8 v = *(const short8*)(src + (size_t)(b*TT + t0 + r)*EE + h*HDD + c*8);
        int sc = kind ? c : (c ^ (r & 7));   // both land at logical^(r&7)
        *(short8*)&ts[r*64 + (sc << 3)] = v;
    }
    __syncthreads();
    #pragma unroll
    for (int rr = 0; rr < 2; ++rr) {
        int oc = tid + rr*256;
        int d = oc & 63, tp = oc >> 6;
        short8 ov; u16* o = (u16*)&ov;
        #pragma unroll
        for (int e = 0; e < 8; ++e) {
            int t = tp*8 + e;
            u16 raw = ts[t*64 + (((d>>3) ^ (t & 7)) << 3) + (d & 7)];
            o[e] = kind ? f2bf(bf2f(raw) * exp2f(l2g * (float)t)) : raw;
        }
        int ptp = tp ^ (d & 7);
        *(short8*)(dst + ((size_t)((b*HH + h)*HDD + d))*TT + t0 + ptp*8) = ov;
    }
}

// ---------------------------------------------------------------------------
// Per-chunk state: Tt[c][d2][d1] = sum_n V[n][d2] * K[n][d1]*gamma^nhat (f32).
// ---------------------------------------------------------------------------
__global__ __launch_bounds__(256)
void chunk_state(const u16* __restrict__ KT, const u16* __restrict__ VT,
                 float* __restrict__ Tb)
{
    __shared__ u16 Ks[64*64], Vs[64*64];
    const int tid = threadIdx.x, w = tid >> 6, lane = tid & 63;
    const int g = lane >> 4, rl = lane & 15;
    const int c = blockIdx.x, h = blockIdx.y, b = blockIdx.z;
    const int t0 = c*64;
    const size_t rowb = (size_t)((b*HH + h)*HDD);
    {
        int cc = tid, r = cc >> 3, ch = cc & 7;
        gload16(KT + (rowb + r)*TT + t0 + ch*8, &Ks[cc*8]);
        gload16(VT + (rowb + r)*TT + t0 + ch*8, &Vs[cc*8]);
        cc = tid + 256; r = cc >> 3; ch = cc & 7;
        gload16(KT + (rowb + r)*TT + t0 + ch*8, &Ks[cc*8]);
        gload16(VT + (rowb + r)*TT + t0 + ch*8, &Vs[cc*8]);
    }
    __syncthreads();
    int d2r = w*16 + rl;
    short8 af0 = *(const short8*)&Vs[d2r*64 + ((g ^ (d2r & 7)) << 3)];
    short8 af1 = *(const short8*)&Vs[d2r*64 + (((4+g) ^ (d2r & 7)) << 3)];
    f32x4 acc[4] = {};
    #pragma unroll
    for (int j = 0; j < 4; ++j) {
        int d1r = j*16 + rl;
        short8 b0 = *(const short8*)&Ks[d1r*64 + ((g ^ (d1r & 7)) << 3)];
        short8 b1 = *(const short8*)&Ks[d1r*64 + (((4+g) ^ (d1r & 7)) << 3)];
        acc[j] = __builtin_amdgcn_mfma_f32_16x16x32_bf16(af0, b0, acc[j], 0, 0, 0);
        acc[j] = __builtin_amdgcn_mfma_f32_16x16x32_bf16(af1, b1, acc[j], 0, 0, 0);
    }
    float* tb = Tb + ((size_t)((b*HH + h)*NC + c))*4096;
    #pragma unroll
    for (int j = 0; j < 4; ++j)
        #pragma unroll
        for (int rr = 0; rr < 4; ++rr)
            tb[(w*16 + g*4 + rr)*64 + j*16 + rl] = acc[j][rr];
}

// ---------------------------------------------------------------------------
// Suffix scan over chunks: Z_c = T_{c+1} + g64*Z_{c+1}, Z_31 = 0.
// ---------------------------------------------------------------------------
__global__ __launch_bounds__(256)
void suffix_scan(const float* __restrict__ Tb, u16* __restrict__ Zb)
{
    __shared__ float lds[NC*512];     // 64 KB
    const int q = blockIdx.x & 7;
    const int h = (blockIdx.x >> 3) & 15;
    const int b = blockIdx.x >> 7;
    const float l2g = log2f(1.f - exp2f(-5.f - (float)h));
    const float g64 = exp2f(l2g * 64.f);
    const float* tb = Tb + ((size_t)((b*HH + h)*NC))*4096 + q*512;
    u16* zb = Zb + ((size_t)((b*HH + h)*NC))*4096;
    const int tid = threadIdx.x;
    #pragma unroll
    for (int k = 0; k < 16; ++k) {
        int i4 = tid + k*256;
        int c = i4 >> 7, r = i4 & 127;
        *(float4*)&lds[c*512 + r*4] = *(const float4*)(tb + (size_t)c*4096 + r*4);
    }
    __syncthreads();
    int e0 = tid*2;
    int d2l = e0 >> 6, d1 = e0 & 63;
    int d2 = q*8 + d2l;
    int pos = d2*64 + (((d1>>3) ^ (d2 & 7)) << 3) + (d1 & 7);
    *(u32*)(zb + (size_t)31*4096 + pos) = 0u;
    float z0 = 0.f, z1 = 0.f;
    for (int c = 30; c >= 0; --c) {
        z0 = lds[(c+1)*512 + e0]     + g64*z0;
        z1 = lds[(c+1)*512 + e0 + 1] + g64*z1;
        u32 pk = (u32)f2bf(z0) | ((u32)f2bf(z1) << 16);
        *(u32*)(zb + (size_t)c*4096 + pos) = pk;
    }
}

// ---------------------------------------------------------------------------
// Output: per chunk c:
//   R = (QK^T/8 * diag decay mask) V  +  0.125*gamma^(64-mhat) * Q . Z_c
// Fused group-norm partial sums via atomics into part2 (zeroed by memset).
// ---------------------------------------------------------------------------
__global__ __launch_bounds__(256)
void ret_out(const u16* __restrict__ Q, const u16* __restrict__ K,
             const u16* __restrict__ VT, const u16* __restrict__ Zb,
             float* __restrict__ R, float* __restrict__ part2)
{
    __shared__ u16 Qs[64*64], Ks[64*64], Vs[64*64], Zs[64*64], Ss[64*64];
    __shared__ float reds[4], redq[4];
    const int tid = threadIdx.x, w = tid >> 6, lane = tid & 63;
    const int g = lane >> 4, rl = lane & 15;
    const int c = blockIdx.x, h = blockIdx.y, b = blockIdx.z;
    const int m0 = c*64;
    const float l2g = log2f(1.f - exp2f(-5.f - (float)h));
    const size_t vrow = (size_t)((b*HH + h)*HDD);
    const u16* zc = Zb + ((size_t)((b*HH + h)*NC + c))*4096;
    {
        int cc = tid, r = cc >> 3, ch = cc & 7;
        gload16(Q  + (size_t)(b*TT + m0 + r)*EE + h*HDD + ch*8, &Qs[cc*8]);
        gload16(K  + (size_t)(b*TT + m0 + r)*EE + h*HDD + ch*8, &Ks[cc*8]);
        gload16(VT + (vrow + r)*TT + m0 + ch*8, &Vs[cc*8]);
        gload16(zc + cc*8, &Zs[cc*8]);
        cc = tid + 256; r = cc >> 3; ch = cc & 7;
        gload16(Q  + (size_t)(b*TT + m0 + r)*EE + h*HDD + ch*8, &Qs[cc*8]);
        gload16(K  + (size_t)(b*TT + m0 + r)*EE + h*HDD + ch*8, &Ks[cc*8]);
        gload16(VT + (vrow + r)*TT + m0 + ch*8, &Vs[cc*8]);
        gload16(zc + cc*8, &Zs[cc*8]);
    }
    __syncthreads();
    const int mr = w*16 + rl;
    short8 qf[2];
    qf[0] = *(const short8*)&Qs[mr*64 + ((g ^ (rl & 7)) << 3)];
    qf[1] = *(const short8*)&Qs[mr*64 + (((4+g) ^ (rl & 7)) << 3)];
    f32x4 sacc[4] = {};
    #pragma unroll
    for (int j = 0; j < 4; ++j) {
        int n = j*16 + rl;
        short8 k0 = *(const short8*)&Ks[n*64 + ((g ^ (n & 7)) << 3)];
        short8 k1 = *(const short8*)&Ks[n*64 + (((4+g) ^ (n & 7)) << 3)];
        sacc[j] = __builtin_amdgcn_mfma_f32_16x16x32_bf16(qf[0], k0, sacc[j], 0, 0, 0);
        sacc[j] = __builtin_amdgcn_mfma_f32_16x16x32_bf16(qf[1], k1, sacc[j], 0, 0, 0);
    }
    float pn[4], pmv[4];
    #pragma unroll
    for (int j = 0; j < 4; ++j) pn[j] = exp2f(l2g * (float)(j*16 + rl));
    #pragma unroll
    for (int rr = 0; rr < 4; ++rr) pmv[rr] = exp2f(-l2g * (float)(w*16 + g*4 + rr));
    #pragma unroll
    for (int j = 0; j < 4; ++j) {
        int nl = j*16 + rl;
        #pragma unroll
        for (int rr = 0; rr < 4; ++rr) {
            int ml = w*16 + g*4 + rr;
            float wgt = (nl >= ml) ? 0.125f * pn[j] * pmv[rr] : 0.f;
            Ss[ml*64 + (((nl>>3) ^ (ml & 7)) << 3) + (nl & 7)] = f2bf(sacc[j][rr] * wgt);
        }
    }
    asm volatile("s_waitcnt lgkmcnt(0)" ::: "memory");  // wave-private S rows
    f32x4 oacc[4] = {}, zacc[4] = {};
    #pragma unroll
    for (int s = 0; s < 2; ++s) {
        short8 sf = *(const short8*)&Ss[mr*64 + (((s*4 + g) ^ (rl & 7)) << 3)];
        #pragma unroll
        for (int j = 0; j < 4; ++j) {
            int d = j*16 + rl;
            short8 vf = *(const short8*)&Vs[d*64 + (((s*4 + g) ^ (d & 7)) << 3)];
            oacc[j] = __builtin_amdgcn_mfma_f32_16x16x32_bf16(sf, vf, oacc[j], 0, 0, 0);
            short8 zf = *(const short8*)&Zs[d*64 + (((s*4 + g) ^ (d & 7)) << 3)];
            zacc[j] = __builtin_amdgcn_mfma_f32_16x16x32_bf16(qf[s], zf, zacc[j], 0, 0, 0);
        }
    }
    const float g64 = exp2f(l2g * 64.f);
    float s = 0.f, sq = 0.f;
    #pragma unroll
    for (int j = 0; j < 4; ++j)
        #pragma unroll
        for (int rr = 0; rr < 4; ++rr) {
            int m_g = m0 + w*16 + g*4 + rr;
            float rs = 0.125f * g64 * pmv[rr];
            float val = oacc[j][rr] + rs*zacc[j][rr];
            R[(size_t)(b*TT + m_g)*EE + h*HDD + j*16 + rl] = val;
            s += val; sq += val*val;
        }
    #pragma unroll
    for (int off = 32; off; off >>= 1) { s += __shfl_down(s, off, 64); sq += __shfl_down(sq, off, 64); }
    if (lane == 0) { reds[w] = s; redq[w] = sq; }
    __syncthreads();
    if (tid == 0) {
        int bh = b*HH + h;
        atomicAdd(&part2[2*bh],   reds[0]+reds[1]+reds[2]+reds[3]);
        atomicAdd(&part2[2*bh+1], redq[0]+redq[1]+redq[2]+redq[3]);
    }
}

// ---------------------------------------------------------------------------
// Z = silu(G) * groupnorm(R); stats recomputed per thread from part2.
// Output bf16 with OLD GEMM-A chunk swizzle (for ring-3 gemm_out).
// ---------------------------------------------------------------------------
__global__ __launch_bounds__(256)
void zgate(const u16* __restrict__ G, const float* __restrict__ R,
           const float* __restrict__ part2, const float* __restrict__ gw,
           const float* __restrict__ gb, u16* __restrict__ Z)
{
    int ci = blockIdx.x*256 + threadIdx.x;
    int row = ci >> 7;
    int c = ci & 127;
    int e0 = c*8;
    int b = row >> 11;
    int bh = b*HH + (e0 >> 6);
    const float inv = 1.f / (float)(TT*HDD);
    float mu = part2[2*bh] * inv;
    float var = part2[2*bh+1] * inv - mu*mu;
    float rs = rsqrtf(var + 1e-5f);
    short8 gv = *(const short8*)(G + (size_t)row*EE + e0);
    const u16* gu = (const u16*)&gv;
    const float* rp = R + (size_t)row*EE + e0;
    float4 r0 = *(const float4*)rp, r1 = *(const float4*)(rp+4);
    float rr[8] = {r0.x,r0.y,r0.z,r0.w,r1.x,r1.y,r1.z,r1.w};
    short8 ov; u16* o = (u16*)&ov;
    #pragma unroll
    for (int q = 0; q < 8; ++q) {
        float gvf = bf2f(gu[q]);
        float gate = gvf / (1.f + __expf(-gvf));
        float nv = (rr[q] - mu)*rs*gw[e0+q] + gb[e0+q];
        o[q] = f2bf(gate*nv);
    }
    int pc = (c & ~3) | ((c & 3) ^ ((row >> 1) & 3));
    *(short8*)(Z + (size_t)row*EE + pc*8) = ov;
}

// ---------------------------------------------------------------------------
extern "C" void kernel_launch(void* const* d_in, const int* in_sizes, int n_in,
                              void* d_out, int out_size, void* d_ws, size_t ws_size,
                              hipStream_t stream)
{
    const float* x  = (const float*)d_in[0];
    const float* Wq = (const float*)d_in[1];
    const float* bq = (const float*)d_in[2];
    const float* Wk = (const float*)d_in[3];
    const float* bk = (const float*)d_in[4];
    const float* Wv = (const float*)d_in[5];
    const float* bv = (const float*)d_in[6];
    const float* Wg = (const float*)d_in[7];
    const float* bg = (const float*)d_in[8];
    const float* Wo = (const float*)d_in[9];
    const float* bo = (const float*)d_in[10];
    const float* gw = (const float*)d_in[11];
    const float* gb = (const float*)d_in[12];
    float* out = (float*)d_out;

    char* p = (char*)d_ws;
    u16* xb  = (u16*)p;              p += (size_t)8<<20;   // x bf16 -> Zbuf -> ZGb
    u16* Wqb = (u16*)p;              p += (size_t)2<<20;
    u16* Wkb = (u16*)p;              p += (size_t)2<<20;
    u16* Wvb = (u16*)p;              p += (size_t)2<<20;
    u16* Wgb = (u16*)p;              p += (size_t)2<<20;
    u16* Wob = (u16*)p;              p += (size_t)2<<20;
    u16* Qb  = (u16*)p;              p += (size_t)8<<20;
    u16* Kb  = (u16*)p;              p += (size_t)8<<20;
    u16* Vb  = (u16*)p;              p += (size_t)8<<20;
    u16* Gb  = (u16*)p;              p += (size_t)8<<20;
    u16* VTb = (u16*)p;              p += (size_t)8<<20;
    u16* KTb = (u16*)p;              p += (size_t)8<<20;
    float* TbRb  = (float*)p;        p += (size_t)16<<20;  // Tb (chunk states) -> Rb
    float* part2 = (float*)p;        p += 4096;
    float* ctab  = (float*)p;        p += (size_t)65536*4;
    float* stab  = (float*)p;        p += (size_t)65536*4;
    u16* Zbuf = xb;                  // x dead after QKVG
    float* Tb = TbRb;
    float* Rb = TbRb;                // ret_out writes after scan reads
    u16* ZGb = xb;                   // zgate output (after ret_out)

    hipMemsetAsync(part2, 0, 64*sizeof(float), stream);
    cvt_swz<<<dim3(2048,1,7), 256, 0, stream>>>(x, Wq, Wk, Wv, Wg, Wo,
                                                xb, Wqb, Wkb, Wvb, Wgb, Wob,
                                                ctab, stab);
    gemm_qkvg<<<dim3(4,16,4), 512, 0, stream>>>(xb, Wqb, Wkb, Wvb, Wgb,
                                                bq, bk, bv, bg, Qb, Kb, Vb, Gb);
    rope_swz<<<dim3(2048,1,2), 256, 0, stream>>>(Qb, Kb, ctab, stab);
    transKV<<<dim3(32,16,4), 256, 0, stream>>>(Vb, Kb, VTb, KTb);
    chunk_state<<<dim3(32,16,2), 256, 0, stream>>>(KTb, VTb, Tb);
    suffix_scan<<<256, 256, 0, stream>>>(Tb, Zbuf);
    ret_out<<<dim3(32,16,2), 256, 0, stream>>>(Qb, Kb, VTb, Zbuf, Rb, part2);
    zgate<<<2048, 256, 0, stream>>>(Gb, Rb, part2, gw, gb, ZGb);
    gemm_out<<<dim3(8,32,1), 256, 0, stream>>>(ZGb, Wob, bo, out);
}

// Round 10
// 216.025 us; speedup vs baseline: 1.0690x; 1.0352x over previous
//
#include <hip/hip_runtime.h>
#include <math.h>

typedef unsigned short u16;
typedef unsigned int u32;
typedef __attribute__((ext_vector_type(8))) short short8;
typedef __attribute__((ext_vector_type(4))) float f32x4;

#define BB 2
#define TT 2048
#define EE 1024
#define HH 16
#define HDD 64
#define NC 32
#define CS 64

__device__ __forceinline__ float bf2f(u16 u){ union{unsigned i; float f;} v; v.i=((unsigned)u)<<16; return v.f; }
__device__ __forceinline__ u16 f2bf(float f){ union{float f; unsigned i;} v; v.f=f; return (u16)((v.i + 0x7fffu + ((v.i>>16)&1u))>>16); }

__device__ __forceinline__ void gload16(const void* g, void* l){
    __builtin_amdgcn_global_load_lds((const __attribute__((address_space(1))) void*)g,
                                     (__attribute__((address_space(3))) void*)l, 16, 0, 0);
}

// ---------------------------------------------------------------------------
// f32 -> bf16 conversion with GEMM chunk swizzle baked into global layout.
// z=0..4 (x, Wq,Wk,Wv,Wg): NEW swizzle (chunk j -> j^(row&7)) for 8-phase GEMM.
// z=5 (Wo): OLD swizzle ((c&3)^((r>>1)&3)) for the ring-3 gemm_out.
// z=6: RoPE trig table.
// ---------------------------------------------------------------------------
__global__ __launch_bounds__(256)
void cvt_swz(const float* __restrict__ s0, const float* __restrict__ s1,
             const float* __restrict__ s2, const float* __restrict__ s3,
             const float* __restrict__ s4, const float* __restrict__ s5,
             u16* __restrict__ d0, u16* __restrict__ d1, u16* __restrict__ d2,
             u16* __restrict__ d3, u16* __restrict__ d4, u16* __restrict__ d5,
             float* __restrict__ ctab, float* __restrict__ stab)
{
    if (blockIdx.z == 6) {
        if (blockIdx.x >= 256) return;
        int idx = blockIdx.x*256 + threadIdx.x;   // 65536
        int t = idx >> 5, f = idx & 31;
        float ang = (float)t * exp2f(-(float)f * (13.287712379549449f/32.f));
        ctab[idx] = cosf(ang);
        stab[idx] = sinf(ang);
        return;
    }
    const float* S; u16* D; int nch; int oldswz = 0;
    switch (blockIdx.z) {
        case 0: S=s0; D=d0; nch=4096*128; break;
        case 1: S=s1; D=d1; nch=1024*128; break;
        case 2: S=s2; D=d2; nch=1024*128; break;
        case 3: S=s3; D=d3; nch=1024*128; break;
        case 4: S=s4; D=d4; nch=1024*128; break;
        default:S=s5; D=d5; nch=1024*128; oldswz=1; break;
    }
    int ci = blockIdx.x*256 + threadIdx.x;
    if (ci >= nch) return;
    int r = ci >> 7, c = ci & 127;
    int pc = oldswz ? ((c & ~3) | ((c & 3) ^ ((r >> 1) & 3)))
                    : ((c & ~7) | ((c & 7) ^ (r & 7)));
    const float4* sp = (const float4*)(S + (size_t)r*EE + c*8);
    float4 f0 = sp[0], f1 = sp[1];
    short8 ov; u16* o = (u16*)&ov;
    o[0]=f2bf(f0.x); o[1]=f2bf(f0.y); o[2]=f2bf(f0.z); o[3]=f2bf(f0.w);
    o[4]=f2bf(f1.x); o[5]=f2bf(f1.y); o[6]=f2bf(f1.z); o[7]=f2bf(f1.w);
    *(short8*)(D + (size_t)r*EE + pc*8) = ov;
}

// ---------------------------------------------------------------------------
// Fused QKVG projections: 256x256 tile, BK=64, 8 waves (2M x 4N), 8-phase
// schedule, double-buffered 128KB LDS, counted vmcnt(4) at phases 4/8 only.
// ---------------------------------------------------------------------------
__global__ __launch_bounds__(512, 2)
void gemm_qkvg(const u16* __restrict__ A,
               const u16* __restrict__ W0, const u16* __restrict__ W1,
               const u16* __restrict__ W2, const u16* __restrict__ W3,
               const float* __restrict__ b0, const float* __restrict__ b1,
               const float* __restrict__ b2, const float* __restrict__ b3,
               u16* __restrict__ C0, u16* __restrict__ C1,
               u16* __restrict__ C2, u16* __restrict__ C3)
{
    __shared__ u16 AS[2][16384];   // 64 KB
    __shared__ u16 BS[2][16384];   // 64 KB
    const u16* W; const float* bias; u16* C; int swz;
    switch (blockIdx.z) {
        case 0: W=W0; bias=b0; C=C0; swz=1; break;
        case 1: W=W1; bias=b1; C=C1; swz=1; break;
        case 2: W=W2; bias=b2; C=C2; swz=0; break;
        default:W=W3; bias=b3; C=C3; swz=0; break;
    }
    const int bm = blockIdx.y*256, bn = blockIdx.x*256;
    const int tid = threadIdx.x;
    const int lane = tid & 63, g = lane >> 4, rl = lane & 15;
    const int w = tid >> 6, wr = w >> 2, wc = w & 3;

    auto stage_half = [&](int isB, int kt, int half){
        const u16* src = isB ? W : A;
        int bb = isB ? bn : bm;
        u16* dst = (isB ? &BS[kt&1][0] : &AS[kt&1][0]) + half*8192;
        #pragma unroll
        for (int r2 = 0; r2 < 2; ++r2) {
            int cc = tid + 512*r2;
            int hr = cc >> 3, pcc = cc & 7;
            gload16(src + (size_t)(bb + half*128 + hr)*EE + kt*64 + pcc*8, dst + cc*8);
        }
    };
    short8 a[8], bf0[4], bf1[4];
    auto read_a = [&](int bi, int Mh){
        const u16* base = &AS[bi][wr*8192];
        #pragma unroll
        for (int mb = 0; mb < 4; ++mb)
          #pragma unroll
          for (int kh = 0; kh < 2; ++kh) {
            int hr = Mh*64 + mb*16 + rl;
            a[mb*2+kh] = *(const short8*)&base[hr*64 + (((kh*4+g) ^ (hr&7)) << 3)];
          }
    };
    auto read_b = [&](short8 (&bf)[4], int bi, int Nh){
        #pragma unroll
        for (int nb = 0; nb < 2; ++nb)
          #pragma unroll
          for (int kh = 0; kh < 2; ++kh) {
            int nr = wc*64 + Nh*32 + nb*16 + rl;
            int half = nr >> 7, hr = nr & 127;
            bf[nb*2+kh] = *(const short8*)&BS[bi][half*8192 + hr*64 + (((kh*4+g) ^ (hr&7)) << 3)];
          }
    };
    f32x4 acc[8][4] = {};
    auto mfma_q = [&](short8 (&bf)[4], int Mh, int Nh){
        __builtin_amdgcn_s_setprio(1);
        #pragma unroll
        for (int mb = 0; mb < 4; ++mb)
          #pragma unroll
          for (int nb = 0; nb < 2; ++nb)
            #pragma unroll
            for (int kh = 0; kh < 2; ++kh)
              acc[Mh*4+mb][Nh*2+nb] = __builtin_amdgcn_mfma_f32_16x16x32_bf16(
                  a[mb*2+kh], bf[nb*2+kh], acc[Mh*4+mb][Nh*2+nb], 0, 0, 0);
        __builtin_amdgcn_s_setprio(0);
    };
    #define BAR()    __builtin_amdgcn_s_barrier()
    #define LGKM0()  { asm volatile("s_waitcnt lgkmcnt(0)" ::: "memory"); __builtin_amdgcn_sched_barrier(0); }
    #define VM4()    asm volatile("s_waitcnt vmcnt(4)" ::: "memory")

    stage_half(0,0,0); stage_half(0,0,1); stage_half(1,0,0); stage_half(1,0,1);
    stage_half(1,1,0); stage_half(1,1,1);
    VM4(); BAR();

    for (int i = 0; i < 7; ++i) {
        int k1 = 2*i+1, k2 = 2*i+2, k3 = 2*i+3;
        read_a(0,0); read_b(bf0,0,0); stage_half(0,k1,0);
        BAR(); LGKM0(); mfma_q(bf0,0,0); BAR();
        read_b(bf1,0,1); stage_half(0,k1,1);
        BAR(); LGKM0(); mfma_q(bf1,0,1); BAR();
        read_a(0,1); stage_half(1,k2,0);
        BAR(); LGKM0(); mfma_q(bf0,1,0); BAR();
        stage_half(1,k2,1); VM4();
        BAR(); mfma_q(bf1,1,1); BAR();
        read_a(1,0); read_b(bf0,1,0); stage_half(0,k2,0);
        BAR(); LGKM0(); mfma_q(bf0,0,0); BAR();
        read_b(bf1,1,1); stage_half(0,k2,1);
        BAR(); LGKM0(); mfma_q(bf1,0,1); BAR();
        read_a(1,1); stage_half(1,k3,0);
        BAR(); LGKM0(); mfma_q(bf0,1,0); BAR();
        stage_half(1,k3,1); VM4();
        BAR(); mfma_q(bf1,1,1); BAR();
    }
    read_a(0,0); read_b(bf0,0,0); stage_half(0,15,0);
    BAR(); LGKM0(); mfma_q(bf0,0,0); BAR();
    read_b(bf1,0,1); stage_half(0,15,1);
    BAR(); LGKM0(); mfma_q(bf1,0,1); BAR();
    read_a(0,1);
    BAR(); LGKM0(); mfma_q(bf0,1,0); BAR();
    asm volatile("s_waitcnt vmcnt(0)" ::: "memory");
    BAR(); mfma_q(bf1,1,1); BAR();
    read_a(1,0); read_b(bf0,1,0);
    BAR(); LGKM0(); mfma_q(bf0,0,0); BAR();
    read_b(bf1,1,1);
    BAR(); LGKM0(); mfma_q(bf1,0,1); BAR();
    read_a(1,1);
    BAR(); LGKM0(); mfma_q(bf0,1,0); BAR();
    mfma_q(bf1,1,1);
    #undef BAR
    #undef LGKM0
    #undef VM4

    float bj[4];
    #pragma unroll
    for (int j = 0; j < 4; ++j) bj[j] = bias[bn + wc*64 + j*16 + rl];
    #pragma unroll
    for (int i = 0; i < 8; ++i)
      #pragma unroll
      for (int rr = 0; rr < 4; ++rr) {
        int m = bm + wr*128 + i*16 + g*4 + rr;
        #pragma unroll
        for (int j = 0; j < 4; ++j) {
            int n = bn + wc*64 + j*16 + rl;
            float v = acc[i][j][rr] + bj[j];
            int col = swz ? ((n & ~63) | ((((n>>3)&7) ^ (m&7)) << 3) | (n & 7)) : n;
            C[(size_t)m*EE + col] = f2bf(v);
        }
      }
}

// ---------------------------------------------------------------------------
// Output projection: 128x128 tile, 4 waves, ring-3 counted-vmcnt schedule.
// ---------------------------------------------------------------------------
__global__ __launch_bounds__(256)
void gemm_out(const u16* __restrict__ A, const u16* __restrict__ W,
              const float* __restrict__ bias, float* __restrict__ C)
{
    __shared__ u16 SA[3][128*32];
    __shared__ u16 SB[3][128*32];
    const int bm = blockIdx.y*128, bn = blockIdx.x*128;
    const int tid = threadIdx.x;
    const int lane = tid & 63, g = lane >> 4, rl = lane & 15;
    const int w = tid >> 6, wr = w >> 1, wc = w & 1;

    auto STAGE = [&](int slot, int kt) {
        int k0 = kt*32;
        #pragma unroll
        for (int r2 = 0; r2 < 2; ++r2) {
            int cc = tid + 256*r2;
            int row = cc >> 2, ch = cc & 3;
            gload16(A + (size_t)(bm + row)*EE + k0 + ch*8, &SA[slot][cc*8]);
        }
        #pragma unroll
        for (int r2 = 0; r2 < 2; ++r2) {
            int cc = tid + 256*r2;
            int row = cc >> 2, ch = cc & 3;
            gload16(W + (size_t)(bn + row)*EE + k0 + ch*8, &SB[slot][cc*8]);
        }
    };

    f32x4 acc[4][4] = {};
    STAGE(0, 0); STAGE(1, 1);
    for (int t = 0; t < 32; ++t) {
        if (t < 31) asm volatile("s_waitcnt vmcnt(4)" ::: "memory");
        else        asm volatile("s_waitcnt vmcnt(0)" ::: "memory");
        __builtin_amdgcn_s_barrier();
        int cur = t % 3;
        if (t + 2 < 32) STAGE((t+2) % 3, t+2);
        const u16* SAc = SA[cur]; const u16* SBc = SB[cur];
        short8 a[4], b[4];
        #pragma unroll
        for (int i = 0; i < 4; ++i) {
            int m = wr*64 + i*16 + rl;
            a[i] = *(const short8*)&SAc[m*32 + ((g ^ ((m>>1)&3)) << 3)];
            int n = wc*64 + i*16 + rl;
            b[i] = *(const short8*)&SBc[n*32 + ((g ^ ((n>>1)&3)) << 3)];
        }
        #pragma unroll
        for (int i = 0; i < 4; ++i)
            #pragma unroll
            for (int j = 0; j < 4; ++j)
                acc[i][j] = __builtin_amdgcn_mfma_f32_16x16x32_bf16(a[i], b[j], acc[i][j], 0, 0, 0);
    }
    float bj[4];
    #pragma unroll
    for (int j = 0; j < 4; ++j) bj[j] = bias[bn + wc*64 + j*16 + rl];
    #pragma unroll
    for (int i = 0; i < 4; ++i)
      #pragma unroll
      for (int rr = 0; rr < 4; ++rr) {
        int m = bm + wr*64 + i*16 + g*4 + rr;
        #pragma unroll
        for (int j = 0; j < 4; ++j) {
            int n = bn + wc*64 + j*16 + rl;
            C[(size_t)m*EE + n] = acc[i][j][rr] + bj[j];
        }
      }
}

// ---------------------------------------------------------------------------
// RoPE in place on d-chunk-swizzled bf16 Q/K.  (round-8 version, restored)
// ---------------------------------------------------------------------------
__global__ __launch_bounds__(256)
void rope_swz(u16* __restrict__ Q, u16* __restrict__ K,
              const float* __restrict__ ctab, const float* __restrict__ stab)
{
    u16* X = blockIdx.z ? K : Q;
    int ci = blockIdx.x*256 + threadIdx.x;
    int row = ci >> 7;
    int t = row & (TT-1);
    int c = ci & 127, h = c >> 3, p = c & 7;
    int d0 = (p ^ (t & 7)) << 3;
    u16* ptr = X + (size_t)row*EE + h*HDD + p*8;
    short8 xv = *(short8*)ptr;
    u16* xu = (u16*)&xv;
    const float* cr = ctab + t*32;
    const float* sr = stab + t*32;
    short8 ov; u16* o = (u16*)&ov;
    #pragma unroll
    for (int q = 0; q < 4; ++q) {
        int j0 = d0 + 2*q;
        float xe = bf2f(xu[2*q]), xo = bf2f(xu[2*q+1]);
        float c0 = cr[j0 & 31],     s0 = sr[j0 & 31];
        float c1 = cr[(j0+1) & 31], s1 = sr[(j0+1) & 31];
        o[2*q]   = f2bf(xe*c0 - xo*s0);
        o[2*q+1] = f2bf(xo*c1 + xe*s1);
    }
    *(short8*)ptr = ov;
}

// ---------------------------------------------------------------------------
// prep2: merged transKV + chunk_state (NO rope inside; K already roped).
// Phase 1: stage K (roped, d-chunk swizzled) and V (plain) rows into LDS.
// Phase 2: transpose; write VT global; keep Vs/Ks in LDS (gamma into Ks).
// Phase 3: T_c[d2][d1] = sum_n V[n][d2]*K[n][d1]*gamma^nhat via MFMA.
// KT is never written to global (saves 32 MB round trip vs round 8).
// ---------------------------------------------------------------------------
__global__ __launch_bounds__(256)
void prep2(const u16* __restrict__ K, const u16* __restrict__ V,
           u16* __restrict__ VT, float* __restrict__ Tb)
{
    __shared__ u16 tsv[64*64], tsk[64*64], Vs[64*64], Ks[64*64];  // 32 KB
    const int tid = threadIdx.x, w = tid >> 6, lane = tid & 63;
    const int g = lane >> 4, rl = lane & 15;
    const int c = blockIdx.x, h = blockIdx.y, b = blockIdx.z;
    const int t0 = c*64;
    const float l2g = log2f(1.f - exp2f(-5.f - (float)h));

    // phase 1: convention = logical chunk lc of row r at position lc^(r&7)
    #pragma unroll
    for (int rr = 0; rr < 2; ++rr) {
        int cc = tid + rr*256;
        int r = cc >> 3, ch = cc & 7;
        int t = t0 + r;
        short8 v = *(const short8*)(V + (size_t)(b*TT + t)*EE + h*HDD + ch*8);
        *(short8*)&tsv[r*64 + ((ch ^ (r & 7)) << 3)] = v;   // V: ch is logical
        short8 kv = *(const short8*)(K + (size_t)(b*TT + t)*EE + h*HDD + ch*8);
        *(short8*)&tsk[r*64 + (ch << 3)] = kv;              // K: ch already lc^(r&7)
    }
    __syncthreads();
    // phase 2: gather transposed rows [d][t]; VT global; Vs/Ks LDS
    #pragma unroll
    for (int rr = 0; rr < 2; ++rr) {
        int oc = tid + rr*256;
        int d = oc & 63, tp = oc >> 6;
        int ptp = tp ^ (d & 7);
        short8 ov; u16* o = (u16*)&ov;
        short8 kv2; u16* k2 = (u16*)&kv2;
        #pragma unroll
        for (int e = 0; e < 8; ++e) {
            int t = tp*8 + e;
            int src = t*64 + (((d>>3) ^ (t & 7)) << 3) + (d & 7);
            o[e]  = tsv[src];
            k2[e] = f2bf(bf2f(tsk[src]) * exp2f(l2g * (float)t));
        }
        *(short8*)(VT + ((size_t)((b*HH + h)*HDD + d))*TT + t0 + ptp*8) = ov;
        *(short8*)&Vs[d*64 + (ptp << 3)] = ov;
        *(short8*)&Ks[d*64 + (ptp << 3)] = kv2;
    }
    __syncthreads();
    // phase 3: chunk state via MFMA (identical to old chunk_state)
    int d2r = w*16 + rl;
    short8 af0 = *(const short8*)&Vs[d2r*64 + ((g ^ (d2r & 7)) << 3)];
    short8 af1 = *(const short8*)&Vs[d2r*64 + (((4+g) ^ (d2r & 7)) << 3)];
    f32x4 acc[4] = {};
    #pragma unroll
    for (int j = 0; j < 4; ++j) {
        int d1r = j*16 + rl;
        short8 b0 = *(const short8*)&Ks[d1r*64 + ((g ^ (d1r & 7)) << 3)];
        short8 b1 = *(const short8*)&Ks[d1r*64 + (((4+g) ^ (d1r & 7)) << 3)];
        acc[j] = __builtin_amdgcn_mfma_f32_16x16x32_bf16(af0, b0, acc[j], 0, 0, 0);
        acc[j] = __builtin_amdgcn_mfma_f32_16x16x32_bf16(af1, b1, acc[j], 0, 0, 0);
    }
    float* tb = Tb + ((size_t)((b*HH + h)*NC + c))*4096;
    #pragma unroll
    for (int j = 0; j < 4; ++j)
        #pragma unroll
        for (int rr = 0; rr < 4; ++rr)
            tb[(w*16 + g*4 + rr)*64 + j*16 + rl] = acc[j][rr];
}

// ---------------------------------------------------------------------------
// Suffix scan over chunks: Z_c = T_{c+1} + g64*Z_{c+1}, Z_31 = 0.
// ---------------------------------------------------------------------------
__global__ __launch_bounds__(256)
void suffix_scan(const float* __restrict__ Tb, u16* __restrict__ Zb)
{
    __shared__ float lds[NC*512];     // 64 KB
    const int q = blockIdx.x & 7;
    const int h = (blockIdx.x >> 3) & 15;
    const int b = blockIdx.x >> 7;
    const float l2g = log2f(1.f - exp2f(-5.f - (float)h));
    const float g64 = exp2f(l2g * 64.f);
    const float* tb = Tb + ((size_t)((b*HH + h)*NC))*4096 + q*512;
    u16* zb = Zb + ((size_t)((b*HH + h)*NC))*4096;
    const int tid = threadIdx.x;
    #pragma unroll
    for (int k = 0; k < 16; ++k) {
        int i4 = tid + k*256;
        int c = i4 >> 7, r = i4 & 127;
        *(float4*)&lds[c*512 + r*4] = *(const float4*)(tb + (size_t)c*4096 + r*4);
    }
    __syncthreads();
    int e0 = tid*2;
    int d2l = e0 >> 6, d1 = e0 & 63;
    int d2 = q*8 + d2l;
    int pos = d2*64 + (((d1>>3) ^ (d2 & 7)) << 3) + (d1 & 7);
    *(u32*)(zb + (size_t)31*4096 + pos) = 0u;
    float z0 = 0.f, z1 = 0.f;
    for (int c = 30; c >= 0; --c) {
        z0 = lds[(c+1)*512 + e0]     + g64*z0;
        z1 = lds[(c+1)*512 + e0 + 1] + g64*z1;
        u32 pk = (u32)f2bf(z0) | ((u32)f2bf(z1) << 16);
        *(u32*)(zb + (size_t)c*4096 + pos) = pk;
    }
}

// ---------------------------------------------------------------------------
// Output (round-8 version): per chunk c, reads ROPED Q/K via gload16.
//   R = (QK^T/8 * diag decay mask) V  +  0.125*gamma^(64-mhat) * Q . Z_c
// Fused group-norm partial sums via atomics into part2 (zeroed by memset).
// ---------------------------------------------------------------------------
__global__ __launch_bounds__(256)
void ret_out(const u16* __restrict__ Q, const u16* __restrict__ K,
             const u16* __restrict__ VT, const u16* __restrict__ Zb,
             float* __restrict__ R, float* __restrict__ part2)
{
    __shared__ u16 Qs[64*64], Ks[64*64], Vs[64*64], Zs[64*64], Ss[64*64];
    __shared__ float reds[4], redq[4];
    const int tid = threadIdx.x, w = tid >> 6, lane = tid & 63;
    const int g = lane >> 4, rl = lane & 15;
    const int c = blockIdx.x, h = blockIdx.y, b = blockIdx.z;
    const int m0 = c*64;
    const float l2g = log2f(1.f - exp2f(-5.f - (float)h));
    const size_t vrow = (size_t)((b*HH + h)*HDD);
    const u16* zc = Zb + ((size_t)((b*HH + h)*NC + c))*4096;
    {
        int cc = tid, r = cc >> 3, ch = cc & 7;
        gload16(Q  + (size_t)(b*TT + m0 + r)*EE + h*HDD + ch*8, &Qs[cc*8]);
        gload16(K  + (size_t)(b*TT + m0 + r)*EE + h*HDD + ch*8, &Ks[cc*8]);
        gload16(VT + (vrow + r)*TT + m0 + ch*8, &Vs[cc*8]);
        gload16(zc + cc*8, &Zs[cc*8]);
        cc = tid + 256; r = cc >> 3; ch = cc & 7;
        gload16(Q  + (size_t)(b*TT + m0 + r)*EE + h*HDD + ch*8, &Qs[cc*8]);
        gload16(K  + (size_t)(b*TT + m0 + r)*EE + h*HDD + ch*8, &Ks[cc*8]);
        gload16(VT + (vrow + r)*TT + m0 + ch*8, &Vs[cc*8]);
        gload16(zc + cc*8, &Zs[cc*8]);
    }
    __syncthreads();
    const int mr = w*16 + rl;
    short8 qf[2];
    qf[0] = *(const short8*)&Qs[mr*64 + ((g ^ (rl & 7)) << 3)];
    qf[1] = *(const short8*)&Qs[mr*64 + (((4+g) ^ (rl & 7)) << 3)];
    f32x4 sacc[4] = {};
    #pragma unroll
    for (int j = 0; j < 4; ++j) {
        int n = j*16 + rl;
        short8 k0 = *(const short8*)&Ks[n*64 + ((g ^ (n & 7)) << 3)];
        short8 k1 = *(const short8*)&Ks[n*64 + (((4+g) ^ (n & 7)) << 3)];
        sacc[j] = __builtin_amdgcn_mfma_f32_16x16x32_bf16(qf[0], k0, sacc[j], 0, 0, 0);
        sacc[j] = __builtin_amdgcn_mfma_f32_16x16x32_bf16(qf[1], k1, sacc[j], 0, 0, 0);
    }
    float pn[4], pmv[4];
    #pragma unroll
    for (int j = 0; j < 4; ++j) pn[j] = exp2f(l2g * (float)(j*16 + rl));
    #pragma unroll
    for (int rr = 0; rr < 4; ++rr) pmv[rr] = exp2f(-l2g * (float)(w*16 + g*4 + rr));
    #pragma unroll
    for (int j = 0; j < 4; ++j) {
        int nl = j*16 + rl;
        #pragma unroll
        for (int rr = 0; rr < 4; ++rr) {
            int ml = w*16 + g*4 + rr;
            float wgt = (nl >= ml) ? 0.125f * pn[j] * pmv[rr] : 0.f;
            Ss[ml*64 + (((nl>>3) ^ (ml & 7)) << 3) + (nl & 7)] = f2bf(sacc[j][rr] * wgt);
        }
    }
    asm volatile("s_waitcnt lgkmcnt(0)" ::: "memory");  // wave-private S rows
    f32x4 oacc[4] = {}, zacc[4] = {};
    #pragma unroll
    for (int s = 0; s < 2; ++s) {
        short8 sf = *(const short8*)&Ss[mr*64 + (((s*4 + g) ^ (rl & 7)) << 3)];
        #pragma unroll
        for (int j = 0; j < 4; ++j) {
            int d = j*16 + rl;
            short8 vf = *(const short8*)&Vs[d*64 + (((s*4 + g) ^ (d & 7)) << 3)];
            oacc[j] = __builtin_amdgcn_mfma_f32_16x16x32_bf16(sf, vf, oacc[j], 0, 0, 0);
            short8 zf = *(const short8*)&Zs[d*64 + (((s*4 + g) ^ (d & 7)) << 3)];
            zacc[j] = __builtin_amdgcn_mfma_f32_16x16x32_bf16(qf[s], zf, zacc[j], 0, 0, 0);
        }
    }
    const float g64 = exp2f(l2g * 64.f);
    float s = 0.f, sq = 0.f;
    #pragma unroll
    for (int j = 0; j < 4; ++j)
        #pragma unroll
        for (int rr = 0; rr < 4; ++rr) {
            int m_g = m0 + w*16 + g*4 + rr;
            float rs = 0.125f * g64 * pmv[rr];
            float val = oacc[j][rr] + rs*zacc[j][rr];
            R[(size_t)(b*TT + m_g)*EE + h*HDD + j*16 + rl] = val;
            s += val; sq += val*val;
        }
    #pragma unroll
    for (int off = 32; off; off >>= 1) { s += __shfl_down(s, off, 64); sq += __shfl_down(sq, off, 64); }
    if (lane == 0) { reds[w] = s; redq[w] = sq; }
    __syncthreads();
    if (tid == 0) {
        int bh = b*HH + h;
        atomicAdd(&part2[2*bh],   reds[0]+reds[1]+reds[2]+reds[3]);
        atomicAdd(&part2[2*bh+1], redq[0]+redq[1]+redq[2]+redq[3]);
    }
}

// ---------------------------------------------------------------------------
// Z = silu(G) * groupnorm(R); stats recomputed per thread from part2.
// ---------------------------------------------------------------------------
__global__ __launch_bounds__(256)
void zgate(const u16* __restrict__ G, const float* __restrict__ R,
           const float* __restrict__ part2, const float* __restrict__ gw,
           const float* __restrict__ gb, u16* __restrict__ Z)
{
    int ci = blockIdx.x*256 + threadIdx.x;
    int row = ci >> 7;
    int c = ci & 127;
    int e0 = c*8;
    int b = row >> 11;
    int bh = b*HH + (e0 >> 6);
    const float inv = 1.f / (float)(TT*HDD);
    float mu = part2[2*bh] * inv;
    float var = part2[2*bh+1] * inv - mu*mu;
    float rs = rsqrtf(var + 1e-5f);
    short8 gv = *(const short8*)(G + (size_t)row*EE + e0);
    const u16* gu = (const u16*)&gv;
    const float* rp = R + (size_t)row*EE + e0;
    float4 r0 = *(const float4*)rp, r1 = *(const float4*)(rp+4);
    float rr[8] = {r0.x,r0.y,r0.z,r0.w,r1.x,r1.y,r1.z,r1.w};
    short8 ov; u16* o = (u16*)&ov;
    #pragma unroll
    for (int q = 0; q < 8; ++q) {
        float gvf = bf2f(gu[q]);
        float gate = gvf / (1.f + __expf(-gvf));
        float nv = (rr[q] - mu)*rs*gw[e0+q] + gb[e0+q];
        o[q] = f2bf(gate*nv);
    }
    int pc = (c & ~3) | ((c & 3) ^ ((row >> 1) & 3));
    *(short8*)(Z + (size_t)row*EE + pc*8) = ov;
}

// ---------------------------------------------------------------------------
extern "C" void kernel_launch(void* const* d_in, const int* in_sizes, int n_in,
                              void* d_out, int out_size, void* d_ws, size_t ws_size,
                              hipStream_t stream)
{
    const float* x  = (const float*)d_in[0];
    const float* Wq = (const float*)d_in[1];
    const float* bq = (const float*)d_in[2];
    const float* Wk = (const float*)d_in[3];
    const float* bk = (const float*)d_in[4];
    const float* Wv = (const float*)d_in[5];
    const float* bv = (const float*)d_in[6];
    const float* Wg = (const float*)d_in[7];
    const float* bg = (const float*)d_in[8];
    const float* Wo = (const float*)d_in[9];
    const float* bo = (const float*)d_in[10];
    const float* gw = (const float*)d_in[11];
    const float* gb = (const float*)d_in[12];
    float* out = (float*)d_out;

    char* p = (char*)d_ws;
    u16* xb  = (u16*)p;              p += (size_t)8<<20;   // x bf16 -> Zbuf -> ZGb
    u16* Wqb = (u16*)p;              p += (size_t)2<<20;
    u16* Wkb = (u16*)p;              p += (size_t)2<<20;
    u16* Wvb = (u16*)p;              p += (size_t)2<<20;
    u16* Wgb = (u16*)p;              p += (size_t)2<<20;
    u16* Wob = (u16*)p;              p += (size_t)2<<20;
    u16* Qb  = (u16*)p;              p += (size_t)8<<20;
    u16* Kb  = (u16*)p;              p += (size_t)8<<20;
    u16* Vb  = (u16*)p;              p += (size_t)8<<20;
    u16* Gb  = (u16*)p;              p += (size_t)8<<20;
    u16* VTb = (u16*)p;              p += (size_t)8<<20;
    float* TbRb  = (float*)p;        p += (size_t)16<<20;  // Tb (chunk states) -> Rb
    float* part2 = (float*)p;        p += 4096;
    float* ctab  = (float*)p;        p += (size_t)65536*4;
    float* stab  = (float*)p;        p += (size_t)65536*4;
    u16* Zbuf = xb;                  // x dead after QKVG
    float* Tb = TbRb;
    float* Rb = TbRb;                // ret_out writes after scan reads
    u16* ZGb = xb;                   // zgate output (after ret_out)

    hipMemsetAsync(part2, 0, 64*sizeof(float), stream);
    cvt_swz<<<dim3(2048,1,7), 256, 0, stream>>>(x, Wq, Wk, Wv, Wg, Wo,
                                                xb, Wqb, Wkb, Wvb, Wgb, Wob,
                                                ctab, stab);
    gemm_qkvg<<<dim3(4,16,4), 512, 0, stream>>>(xb, Wqb, Wkb, Wvb, Wgb,
                                                bq, bk, bv, bg, Qb, Kb, Vb, Gb);
    rope_swz<<<dim3(2048,1,2), 256, 0, stream>>>(Qb, Kb, ctab, stab);
    prep2<<<dim3(32,16,2), 256, 0, stream>>>(Kb, Vb, VTb, Tb);
    suffix_scan<<<256, 256, 0, stream>>>(Tb, Zbuf);
    ret_out<<<dim3(32,16,2), 256, 0, stream>>>(Qb, Kb, VTb, Zbuf, Rb, part2);
    zgate<<<2048, 256, 0, stream>>>(Gb, Rb, part2, gw, gb, ZGb);
    gemm_out<<<dim3(8,32,1), 256, 0, stream>>>(ZGb, Wob, bo, out);
}